// Round 5
// baseline (501.694 us; speedup 1.0000x reference)
//
#include <hip/hip_runtime.h>
#include <hip/hip_bf16.h>

#define NQ 65536
#define DIM 512
#define HID 256
#define NWAY 5
#define NKPTS 17

typedef short bf16x8 __attribute__((ext_vector_type(8)));
typedef float f32x4 __attribute__((ext_vector_type(4)));

static __device__ __forceinline__ unsigned short f2bf(float f) {
    unsigned int x = __float_as_uint(f);
    unsigned int r = (x + 0x7fffu + ((x >> 16) & 1u)) >> 16;
    return (unsigned short)r;
}

// ---------------- L1: support layer1 (coalesced outer-product) + [Wo1|Wc1] transpose ----------------
// bx<50: block=(s,chalf): h1[s][c] = relu(sf[s]·W1[:,c]+b1[c]); W1 read row-coalesced.
// bx>=50: 64x64 tile transpose+bf16 of [Wo1|Wc1] -> wb[c*512+k]
__global__ __launch_bounds__(256) void k_l1(const float* __restrict__ sf,
                                            const float* __restrict__ W1, const float* __restrict__ b1,
                                            const float* __restrict__ Wo1, const float* __restrict__ Wc1,
                                            float* __restrict__ ws_h1, unsigned short* __restrict__ wb) {
    int bx = blockIdx.x, t = threadIdx.x;
    if (bx < 50) {
        __shared__ float s_sf[DIM];
        int s = bx >> 1, c = (bx & 1) * 256 + t;
        s_sf[t] = sf[s * DIM + t];
        s_sf[t + 256] = sf[s * DIM + 256 + t];
        __syncthreads();
        float acc = 0.0f;
        #pragma unroll 8
        for (int k = 0; k < DIM; k++) acc += W1[k * DIM + c] * s_sf[k];
        ws_h1[s * DIM + c] = fmaxf(acc + b1[c], 0.0f);
    } else {
        __shared__ unsigned short T[64][72];
        int tb = bx - 50;                    // 0..63
        const float* src = (tb < 32) ? Wo1 : Wc1;
        int cofs = (tb < 32) ? 0 : 256;
        int tt = tb & 31;
        int kt = tt >> 2;                    // k-tile 0..7
        int ct = tt & 3;                     // c-tile 0..3
        int i = t >> 2;                      // k row within tile 0..63
        int qd = t & 3;
        const float* rp = src + (size_t)(kt * 64 + i) * HID + ct * 64 + qd * 16;
        #pragma unroll
        for (int v = 0; v < 4; v++) {
            float4 x = *(const float4*)(rp + v * 4);
            T[qd * 16 + v * 4 + 0][i] = f2bf(x.x);
            T[qd * 16 + v * 4 + 1][i] = f2bf(x.y);
            T[qd * 16 + v * 4 + 2][i] = f2bf(x.z);
            T[qd * 16 + v * 4 + 3][i] = f2bf(x.w);
        }
        __syncthreads();
        int j = t >> 2;                      // c within tile
        int part = t & 3;
        uint4 o0 = *(const uint4*)&T[j][part * 16];
        uint4 o1 = *(const uint4*)&T[j][part * 16 + 8];
        unsigned short* dst = wb + (size_t)(cofs + ct * 64 + j) * DIM + kt * 64 + part * 16;
        *(uint4*)dst = o0;
        *(uint4*)(dst + 8) = o1;
    }
}

// ---------------- L2: protos (mean commutes with layer2) + norms, coalesced ----------------
// block w in 0..4: proto[w][c] = (mean_s h1[w*5+s]) @ W2[:,c] + b2[c]; pn[w]=||proto||
__global__ __launch_bounds__(256) void k_l2(const float* __restrict__ ws_h1,
                                            const float* __restrict__ W2, const float* __restrict__ b2,
                                            float* __restrict__ ws_proto, float* __restrict__ ws_pn) {
    __shared__ float s_m[DIM];
    __shared__ float red[256];
    int w = blockIdx.x, t = threadIdx.x;
    for (int k = t; k < DIM; k += 256) {
        float m = 0.0f;
        #pragma unroll
        for (int s = 0; s < 5; s++) m += ws_h1[(w * 5 + s) * DIM + k];
        s_m[k] = m * 0.2f;
    }
    __syncthreads();
    float a0 = 0.0f, a1 = 0.0f;
    int c0 = t, c1 = t + 256;
    #pragma unroll 8
    for (int k = 0; k < DIM; k++) {
        float mk = s_m[k];
        a0 += W2[k * DIM + c0] * mk;
        a1 += W2[k * DIM + c1] * mk;
    }
    float v0 = a0 + b2[c0], v1 = a1 + b2[c1];
    ws_proto[w * DIM + c0] = v0;
    ws_proto[w * DIM + c1] = v1;
    red[t] = v0 * v0 + v1 * v1;
    __syncthreads();
    for (int s2 = 128; s2 > 0; s2 >>= 1) {
        if (t < s2) red[t] += red[t + s2];
        __syncthreads();
    }
    if (t == 0) ws_pn[w] = sqrtf(red[0]);
}

// ---------------- L3: distances (pure f32) + argmin + out_proto broadcast ----------------
// 2048 blocks x 256; wave handles 8 query rows; protos live in registers.
__global__ __launch_bounds__(256) void k_cd(const float* __restrict__ qf,
                                            const float* __restrict__ ws_proto, const float* __restrict__ ws_pn,
                                            const float* __restrict__ temp_p,
                                            float* __restrict__ out_dist, float* __restrict__ out_class,
                                            float* __restrict__ out_proto) {
    __shared__ float dl[32][5];
    __shared__ float cl[32];
    int bx = blockIdx.x, t = threadIdx.x;
    int wv = t >> 6, lane = t & 63;

    if (bx < NWAY * NKPTS && t < 128) {
        f32x4 v = *(const f32x4*)(ws_proto + (bx / NKPTS) * DIM + t * 4);
        *(f32x4*)(out_proto + (size_t)bx * DIM + t * 4) = v;
    }

    float p[NWAY][8];
    #pragma unroll
    for (int w = 0; w < NWAY; w++) {
        f32x4 u0 = *(const f32x4*)(ws_proto + w * DIM + lane * 8);
        f32x4 u1 = *(const f32x4*)(ws_proto + w * DIM + lane * 8 + 4);
        p[w][0] = u0[0]; p[w][1] = u0[1]; p[w][2] = u0[2]; p[w][3] = u0[3];
        p[w][4] = u1[0]; p[w][5] = u1[1]; p[w][6] = u1[2]; p[w][7] = u1[3];
    }
    float pn[NWAY];
    #pragma unroll
    for (int w = 0; w < NWAY; w++) pn[w] = ws_pn[w];
    float invt = 1.0f / temp_p[0];

    for (int i = 0; i < 8; i++) {
        int rloc = wv * 8 + i;
        size_t rq = (size_t)bx * 32 + rloc;
        const float4* qp = (const float4*)(qf + rq * DIM + lane * 8);
        float4 a = qp[0], b = qp[1];
        float qv[8] = {a.x, a.y, a.z, a.w, b.x, b.y, b.z, b.w};
        float s[6] = {0, 0, 0, 0, 0, 0};
        #pragma unroll
        for (int j = 0; j < 8; j++) {
            float v = qv[j];
            s[5] += v * v;
            #pragma unroll
            for (int w = 0; w < NWAY; w++) s[w] += v * p[w][j];
        }
        #pragma unroll
        for (int off = 32; off > 0; off >>= 1)
            #pragma unroll
            for (int k = 0; k < 6; k++) s[k] += __shfl_xor(s[k], off, 64);
        if (lane == 0) {
            float qn = sqrtf(s[5]);
            float mv = 1e30f;
            int ami = 0;
            #pragma unroll
            for (int w = 0; w < NWAY; w++) {
                float den = fmaxf(qn * pn[w], 1e-8f);
                float d = (1.0f - s[w] / den) * invt;
                dl[rloc][w] = d;
                if (d < mv) { mv = d; ami = w; }
            }
            cl[rloc] = (float)ami;
        }
    }
    __syncthreads();
    for (int i = t; i < 32 * NWAY * NKPTS; i += 256) {
        int q = i / (NWAY * NKPTS);
        int rem = i - q * (NWAY * NKPTS);
        out_dist[(size_t)bx * 32 * (NWAY * NKPTS) + i] = dl[q][rem / NKPTS];
    }
    if (t < 32) out_class[(size_t)bx * 32 + t] = cl[t];
}

// ---------------- L4: MFMA GEMM (M=64, N=512 both heads) + register epilogue ----------------
__global__ __launch_bounds__(256) void k_gemm(const float* __restrict__ qf, const unsigned short* __restrict__ wb,
                                              const float* __restrict__ bo1, const float* __restrict__ Wo2,
                                              const float* __restrict__ bo2,
                                              const float* __restrict__ bc1, const float* __restrict__ Wc2,
                                              const float* __restrict__ bc2,
                                              const float* __restrict__ ic,
                                              float* __restrict__ out_kp, float* __restrict__ out_conf) {
    __shared__ __align__(16) unsigned short Alds[64 * 40];    // stride 40 bf16
    __shared__ __align__(16) unsigned short Blds[512 * 40];   // stride 40 bf16
    __shared__ float exo[2][64], eyo[2][64], ecf[2][64];
    __shared__ float fin[3][64];

    int mb = blockIdx.x;
    int t = threadIdx.x;
    int wv = t >> 6;
    int lane = t & 63;
    int r = lane & 15;
    int q8 = (lane >> 4) * 8;

    f32x4 acc[4][8];
    #pragma unroll
    for (int i = 0; i < 4; i++)
        #pragma unroll
        for (int j = 0; j < 8; j++) {
            f32x4 z = {0.0f, 0.0f, 0.0f, 0.0f};
            acc[i][j] = z;
        }

    int am = t >> 2;   // A row staged by this thread
    int akc = t & 3;   // k-chunk *8
    const float* aptr = qf + ((size_t)(mb * 64 + am)) * DIM + akc * 8;
    // B chunks: j=0..7, chunk=j*256+t -> col=chunk>>2, kc=chunk&3
    const unsigned short* bptr[8];
    int bldsoff[8];
    #pragma unroll
    for (int j = 0; j < 8; j++) {
        int chunk = j * 256 + t;
        int col = chunk >> 2, kc = chunk & 3;
        bptr[j] = wb + (size_t)col * DIM + kc * 8;
        bldsoff[j] = col * 40 + kc * 8;
    }

    float4 A0 = *(const float4*)(aptr);
    float4 A1 = *(const float4*)(aptr + 4);
    uint4 Bp[8];
    #pragma unroll
    for (int j = 0; j < 8; j++) Bp[j] = *(const uint4*)(bptr[j]);

    for (int it = 0; it < 16; it++) {
        unsigned int p0 = f2bf(A0.x) | ((unsigned int)f2bf(A0.y) << 16);
        unsigned int p1 = f2bf(A0.z) | ((unsigned int)f2bf(A0.w) << 16);
        unsigned int p2 = f2bf(A1.x) | ((unsigned int)f2bf(A1.y) << 16);
        unsigned int p3 = f2bf(A1.z) | ((unsigned int)f2bf(A1.w) << 16);
        __syncthreads();  // previous iter frag reads complete
        *(uint4*)(Alds + am * 40 + akc * 8) = make_uint4(p0, p1, p2, p3);
        #pragma unroll
        for (int j = 0; j < 8; j++) *(uint4*)(Blds + bldsoff[j]) = Bp[j];
        __syncthreads();
        if (it < 15) {  // prefetch stays in flight across the MFMA body
            int k1 = (it + 1) * 32;
            A0 = *(const float4*)(aptr + k1);
            A1 = *(const float4*)(aptr + k1 + 4);
            #pragma unroll
            for (int j = 0; j < 8; j++) Bp[j] = *(const uint4*)(bptr[j] + k1);
        }
        bf16x8 af[4], bf[8];
        #pragma unroll
        for (int mt = 0; mt < 4; mt++)
            af[mt] = *(const bf16x8*)(Alds + (mt * 16 + r) * 40 + q8);
        #pragma unroll
        for (int nt = 0; nt < 8; nt++)
            bf[nt] = *(const bf16x8*)(Blds + (wv * 128 + nt * 16 + r) * 40 + q8);
        #pragma unroll
        for (int mt = 0; mt < 4; mt++)
            #pragma unroll
            for (int nt = 0; nt < 8; nt++)
                acc[mt][nt] = __builtin_amdgcn_mfma_f32_16x16x32_bf16(af[mt], bf[nt], acc[mt][nt], 0, 0, 0);
    }

    // ---- register epilogue: h=relu(acc+b1), second layer via per-lane FMA + shfl reduce ----
    // C layout: row = mt*16 + (lane>>4)*4 + rg, col = wv*128 + nt*16 + (lane&15)
    float bv[8], wx[8], wy[8];
    if (wv < 2) {
        #pragma unroll
        for (int nt = 0; nt < 8; nt++) {
            int col = wv * 128 + nt * 16 + r;
            bv[nt] = bo1[col];
            wx[nt] = Wo2[col * 2];
            wy[nt] = Wo2[col * 2 + 1];
        }
    } else {
        #pragma unroll
        for (int nt = 0; nt < 8; nt++) {
            int cc = (wv - 2) * 128 + nt * 16 + r;
            bv[nt] = bc1[cc];
            wx[nt] = Wc2[cc];
            wy[nt] = 0.0f;
        }
    }
    #pragma unroll
    for (int mt = 0; mt < 4; mt++)
        #pragma unroll
        for (int rg = 0; rg < 4; rg++) {
            float hx = 0.0f, hy = 0.0f;
            #pragma unroll
            for (int nt = 0; nt < 8; nt++) {
                float h = fmaxf(acc[mt][nt][rg] + bv[nt], 0.0f);
                hx += h * wx[nt];
                hy += h * wy[nt];
            }
            #pragma unroll
            for (int off = 1; off <= 8; off <<= 1) {
                hx += __shfl_xor(hx, off, 64);
                hy += __shfl_xor(hy, off, 64);
            }
            if (r == 0) {
                int row = mt * 16 + (lane >> 4) * 4 + rg;
                if (wv < 2) { exo[wv][row] = hx; eyo[wv][row] = hy; }
                else        { ecf[wv - 2][row] = hx; }
            }
        }
    __syncthreads();
    if (t < 64) {
        size_t Q = (size_t)mb * 64 + t;
        float ox = exo[0][t] + exo[1][t] + bo2[0];
        float oy = eyo[0][t] + eyo[1][t] + bo2[1];
        float cf = ecf[0][t] + ecf[1][t] + bc2[0];
        fin[0][t] = (1.0f / (1.0f + __expf(-ox))) * ic[Q * 2];
        fin[1][t] = (1.0f / (1.0f + __expf(-oy))) * ic[Q * 2 + 1];
        fin[2][t] = 1.0f / (1.0f + __expf(-cf));
    }
    __syncthreads();
    for (int i = t; i < 64 * 34; i += 256) {
        int q = i / 34;
        int rem = i - q * 34;
        out_kp[(size_t)mb * 64 * 34 + i] = fin[rem & 1][q];
    }
    for (int i = t; i < 64 * 17; i += 256)
        out_conf[(size_t)mb * 64 * 17 + i] = fin[2][i / 17];
}

extern "C" void kernel_launch(void* const* d_in, const int* in_sizes, int n_in,
                              void* d_out, int out_size, void* d_ws, size_t ws_size,
                              hipStream_t stream) {
    const float* sf = (const float*)d_in[0];
    const float* qf = (const float*)d_in[2];
    const float* ic = (const float*)d_in[3];
    const float* W1 = (const float*)d_in[4];
    const float* b1 = (const float*)d_in[5];
    const float* W2 = (const float*)d_in[6];
    const float* b2 = (const float*)d_in[7];
    const float* Wo1 = (const float*)d_in[8];
    const float* bo1 = (const float*)d_in[9];
    const float* Wo2 = (const float*)d_in[10];
    const float* bo2 = (const float*)d_in[11];
    const float* Wc1 = (const float*)d_in[12];
    const float* bc1 = (const float*)d_in[13];
    const float* Wc2 = (const float*)d_in[14];
    const float* bc2 = (const float*)d_in[15];
    const float* temp = (const float*)d_in[16];

    float* out = (float*)d_out;
    float* out_kp = out;                   // 65536*17*2
    float* out_conf = out + 2228224;       // 65536*17
    float* out_dist = out + 3342336;       // 65536*5*17
    float* out_class = out + 8912896;      // 65536
    float* out_proto = out + 8978432;      // 5*17*512

    char* ws = (char*)d_ws;
    float* ws_h1 = (float*)ws;                             // 25*512 f32
    float* ws_proto = (float*)(ws + 51200);                // 5*512 f32
    float* ws_pn = (float*)(ws + 61440);                   // 5 f32
    unsigned short* ws_wb = (unsigned short*)(ws + 65536); // 512*512 bf16 (transposed [Wo1|Wc1])

    hipLaunchKernelGGL(k_l1, dim3(114), dim3(256), 0, stream, sf, W1, b1, Wo1, Wc1, ws_h1, ws_wb);
    hipLaunchKernelGGL(k_l2, dim3(5), dim3(256), 0, stream, ws_h1, W2, b2, ws_proto, ws_pn);
    hipLaunchKernelGGL(k_cd, dim3(2048), dim3(256), 0, stream, qf, ws_proto, ws_pn, temp,
                       out_dist, out_class, out_proto);
    hipLaunchKernelGGL(k_gemm, dim3(1024), dim3(256), 0, stream, qf, ws_wb,
                       bo1, Wo2, bo2, bc1, Wc2, bc2, ic, out_kp, out_conf);
}

// Round 6
// 391.720 us; speedup vs baseline: 1.2807x; 1.2807x over previous
//
#include <hip/hip_runtime.h>
#include <hip/hip_bf16.h>

#define NQ 65536
#define DIM 512
#define HID 256
#define NWAY 5
#define NKPTS 17

typedef short bf16x8 __attribute__((ext_vector_type(8)));
typedef float f32x4 __attribute__((ext_vector_type(4)));
typedef _Float16 half8 __attribute__((ext_vector_type(8)));

static __device__ __forceinline__ unsigned short f2bf(float f) {
    unsigned int x = __float_as_uint(f);
    unsigned int r = (x + 0x7fffu + ((x >> 16) & 1u)) >> 16;
    return (unsigned short)r;
}
// bank-conflict-avoiding chunk swizzle: 16B chunk c of row r stored at c ^ swz(r)
static __device__ __forceinline__ int swz(int r) { return (r ^ (r >> 2)) & 3; }

static __device__ __forceinline__ void ldg_lds16(const void* g, void* l) {
    __builtin_amdgcn_global_load_lds(
        (const __attribute__((address_space(1))) unsigned int*)g,
        (__attribute__((address_space(3))) unsigned int*)l, 16, 0, 0);
}

// ---------------- k_l1: support layer1 (coalesced) + [Wo1|Wc1] -> tiled/swizzled bf16 wbT ----------
// wbT layout (bf16 units): it*16384 + col*32 + ((kc ^ swz(col&15))*8) + (k&7);  it=k>>5, kc=(k>>3)&3
__global__ __launch_bounds__(256) void k_l1(const float* __restrict__ sf,
                                            const float* __restrict__ W1, const float* __restrict__ b1,
                                            const float* __restrict__ Wo1, const float* __restrict__ Wc1,
                                            float* __restrict__ ws_h1, unsigned short* __restrict__ wbT) {
    int bx = blockIdx.x, t = threadIdx.x;
    if (bx < 50) {
        __shared__ float s_sf[DIM];
        int s = bx >> 1, c = (bx & 1) * 256 + t;
        s_sf[t] = sf[s * DIM + t];
        s_sf[t + 256] = sf[s * DIM + 256 + t];
        __syncthreads();
        float acc = 0.0f;
        #pragma unroll 8
        for (int k = 0; k < DIM; k++) acc += W1[k * DIM + c] * s_sf[k];
        ws_h1[s * DIM + c] = fmaxf(acc + b1[c], 0.0f);
    } else {
        __shared__ unsigned short T[64][72];
        int tb = bx - 50;                    // 0..63
        const float* src = (tb < 32) ? Wo1 : Wc1;
        int cofs = (tb < 32) ? 0 : 256;
        int tt = tb & 31;
        int kt = tt >> 2;                    // k-tile 0..7
        int ct = tt & 3;                     // c-tile 0..3
        int i = t >> 2;                      // k row within tile 0..63
        int qd = t & 3;
        const float* rp = src + (size_t)(kt * 64 + i) * HID + ct * 64 + qd * 16;
        #pragma unroll
        for (int v = 0; v < 4; v++) {
            float4 x = *(const float4*)(rp + v * 4);
            T[qd * 16 + v * 4 + 0][i] = f2bf(x.x);
            T[qd * 16 + v * 4 + 1][i] = f2bf(x.y);
            T[qd * 16 + v * 4 + 2][i] = f2bf(x.z);
            T[qd * 16 + v * 4 + 3][i] = f2bf(x.w);
        }
        __syncthreads();
        int j = t >> 2;                      // c within tile
        int part = t & 3;
        uint4 o0 = *(const uint4*)&T[j][part * 16];      // k = kt*64+part*16 .. +7
        uint4 o1 = *(const uint4*)&T[j][part * 16 + 8];  // k = +8 .. +15
        int col = cofs + ct * 64 + j;
        int k0 = kt * 64 + part * 16;
        int it0 = k0 >> 5;
        int kc0 = (k0 >> 3) & 3;             // in {0,2}
        int s = swz(j & 15);
        unsigned short* base = wbT + it0 * 16384 + col * 32;
        *(uint4*)(base + ((kc0 ^ s) * 8)) = o0;
        *(uint4*)(base + (((kc0 + 1) ^ s) * 8)) = o1;
    }
}

// ---------------- k_l2: prototypes (mean commutes with layer2) + norms ----------------
__global__ __launch_bounds__(256) void k_l2(const float* __restrict__ ws_h1,
                                            const float* __restrict__ W2, const float* __restrict__ b2,
                                            float* __restrict__ ws_proto, float* __restrict__ ws_pn) {
    __shared__ float s_m[DIM];
    __shared__ float red[256];
    int w = blockIdx.x, t = threadIdx.x;
    for (int k = t; k < DIM; k += 256) {
        float m = 0.0f;
        #pragma unroll
        for (int s = 0; s < 5; s++) m += ws_h1[(w * 5 + s) * DIM + k];
        s_m[k] = m * 0.2f;
    }
    __syncthreads();
    float a0 = 0.0f, a1 = 0.0f;
    int c0 = t, c1 = t + 256;
    #pragma unroll 8
    for (int k = 0; k < DIM; k++) {
        float mk = s_m[k];
        a0 += W2[k * DIM + c0] * mk;
        a1 += W2[k * DIM + c1] * mk;
    }
    float v0 = a0 + b2[c0], v1 = a1 + b2[c1];
    ws_proto[w * DIM + c0] = v0;
    ws_proto[w * DIM + c1] = v1;
    red[t] = v0 * v0 + v1 * v1;
    __syncthreads();
    for (int s2 = 128; s2 > 0; s2 >>= 1) {
        if (t < s2) red[t] += red[t + s2];
        __syncthreads();
    }
    if (t == 0) ws_pn[w] = sqrtf(red[0]);
}

// ---------------- k_cd: distances (pure f32) + argmin + out_proto + optional qf->bf16 tiling ----
// qb layout (bytes): mb*65536 + it*4096 + row*64 + ((kc^swz(row))*16); row=q&63, mb=q>>6
__global__ __launch_bounds__(256) void k_cd(const float* __restrict__ qf,
                                            const float* __restrict__ ws_proto, const float* __restrict__ ws_pn,
                                            const float* __restrict__ temp_p,
                                            float* __restrict__ out_dist, float* __restrict__ out_class,
                                            float* __restrict__ out_proto,
                                            unsigned short* __restrict__ qb, int do_qb) {
    __shared__ float dl[32][5];
    __shared__ float cl[32];
    int bx = blockIdx.x, t = threadIdx.x;
    int wv = t >> 6, lane = t & 63;

    if (bx < NWAY * NKPTS && t < 128) {
        f32x4 v = *(const f32x4*)(ws_proto + (bx / NKPTS) * DIM + t * 4);
        *(f32x4*)(out_proto + (size_t)bx * DIM + t * 4) = v;
    }

    float p[NWAY][8];
    #pragma unroll
    for (int w = 0; w < NWAY; w++) {
        f32x4 u0 = *(const f32x4*)(ws_proto + w * DIM + lane * 8);
        f32x4 u1 = *(const f32x4*)(ws_proto + w * DIM + lane * 8 + 4);
        p[w][0] = u0[0]; p[w][1] = u0[1]; p[w][2] = u0[2]; p[w][3] = u0[3];
        p[w][4] = u1[0]; p[w][5] = u1[1]; p[w][6] = u1[2]; p[w][7] = u1[3];
    }
    float pn[NWAY];
    #pragma unroll
    for (int w = 0; w < NWAY; w++) pn[w] = ws_pn[w];
    float invt = 1.0f / temp_p[0];

    int itc = lane >> 2, kcc = lane & 3;   // this lane's qb chunk coords (k = lane*8..+7)
    #pragma unroll
    for (int i = 0; i < 8; i++) {
        int rloc = wv * 8 + i;
        size_t rq = (size_t)bx * 32 + rloc;
        const float4* qp = (const float4*)(qf + rq * DIM + lane * 8);
        float4 a = qp[0], b = qp[1];
        float qv[8] = {a.x, a.y, a.z, a.w, b.x, b.y, b.z, b.w};
        if (do_qb) {
            unsigned int p0 = f2bf(qv[0]) | ((unsigned int)f2bf(qv[1]) << 16);
            unsigned int p1 = f2bf(qv[2]) | ((unsigned int)f2bf(qv[3]) << 16);
            unsigned int p2 = f2bf(qv[4]) | ((unsigned int)f2bf(qv[5]) << 16);
            unsigned int p3 = f2bf(qv[6]) | ((unsigned int)f2bf(qv[7]) << 16);
            int row = (int)(rq & 63);
            size_t mb2 = rq >> 6;
            char* dst = (char*)qb + mb2 * 65536 + itc * 4096 + row * 64 + ((kcc ^ swz(row)) << 4);
            *(uint4*)dst = make_uint4(p0, p1, p2, p3);
        }
        float s[6] = {0, 0, 0, 0, 0, 0};
        #pragma unroll
        for (int j = 0; j < 8; j++) {
            float v = qv[j];
            s[5] += v * v;
            #pragma unroll
            for (int w = 0; w < NWAY; w++) s[w] += v * p[w][j];
        }
        #pragma unroll
        for (int off = 32; off > 0; off >>= 1)
            #pragma unroll
            for (int k = 0; k < 6; k++) s[k] += __shfl_xor(s[k], off, 64);
        if (lane == 0) {
            float qn = sqrtf(s[5]);
            float mv = 1e30f;
            int ami = 0;
            #pragma unroll
            for (int w = 0; w < NWAY; w++) {
                float den = fmaxf(qn * pn[w], 1e-8f);
                float d = (1.0f - s[w] / den) * invt;
                dl[rloc][w] = d;
                if (d < mv) { mv = d; ami = w; }
            }
            cl[rloc] = (float)ami;
        }
    }
    __syncthreads();
    for (int i = t; i < 32 * NWAY * NKPTS; i += 256) {
        int q = i / (NWAY * NKPTS);
        int rem = i - q * (NWAY * NKPTS);
        out_dist[(size_t)bx * 32 * (NWAY * NKPTS) + i] = dl[q][rem / NKPTS];
    }
    if (t < 32) out_class[(size_t)bx * 32 + t] = cl[t];
}

// ---------------- shared epilogue (R2-verified): h=relu(C+b1) -> LDS f16 -> head2 + sigmoid ----
static __device__ __forceinline__ void epilogue(f32x4 acc[4][4], char* smem, int mb, int nb,
                                                int t, int wv, int lane, int r,
                                                const float* __restrict__ bo1, const float* __restrict__ Wo2,
                                                const float* __restrict__ bo2,
                                                const float* __restrict__ bc1, const float* __restrict__ Wc2,
                                                const float* __restrict__ bc2,
                                                const float* __restrict__ ic,
                                                float* __restrict__ out_kp, float* __restrict__ out_conf) {
    _Float16* hlds = (_Float16*)smem;              // 64 x stride 264 f16
    float* offlds = (float*)(smem + 33792);        // 128 f32
    const float* bias = nb ? bc1 : bo1;
    #pragma unroll
    for (int nt = 0; nt < 4; nt++) {
        int cl = wv * 64 + nt * 16 + r;
        float bv = bias[cl];
        #pragma unroll
        for (int mt = 0; mt < 4; mt++)
            #pragma unroll
            for (int rg = 0; rg < 4; rg++) {
                int ml = mt * 16 + (lane >> 4) * 4 + rg;
                float v = acc[mt][nt][rg] + bv;
                hlds[ml * 264 + cl] = (_Float16)fmaxf(v, 0.0f);
            }
    }
    __syncthreads();
    if (nb == 0) {
        if (t < 64) {
            float ox = bo2[0], oy = bo2[1];
            for (int c0 = 0; c0 < 256; c0 += 8) {
                half8 hv = *(const half8*)(hlds + t * 264 + c0);
                #pragma unroll
                for (int j = 0; j < 8; j++) {
                    float hf = (float)hv[j];
                    ox += hf * Wo2[(c0 + j) * 2];
                    oy += hf * Wo2[(c0 + j) * 2 + 1];
                }
            }
            offlds[t * 2] = ox;
            offlds[t * 2 + 1] = oy;
        }
        __syncthreads();
        for (int i = t; i < 64 * 34; i += 256) {
            int q = i / 34;
            int rem = i - q * 34;
            int j = rem & 1;
            size_t Q = (size_t)mb * 64 + q;
            float o = offlds[q * 2 + j];
            float sg = 1.0f / (1.0f + __expf(-o));
            out_kp[Q * 34 + rem] = sg * ic[Q * 2 + j];
        }
    } else {
        if (t < 64) {
            float cl2 = bc2[0];
            for (int c0 = 0; c0 < 256; c0 += 8) {
                half8 hv = *(const half8*)(hlds + t * 264 + c0);
                #pragma unroll
                for (int j = 0; j < 8; j++) cl2 += (float)hv[j] * Wc2[c0 + j];
            }
            offlds[t] = 1.0f / (1.0f + __expf(-cl2));
        }
        __syncthreads();
        for (int i = t; i < 64 * 17; i += 256) {
            int q = i / 17;
            out_conf[(size_t)mb * 64 * 17 + i] = offlds[q];
        }
    }
}

// ---------------- k_ga: async double-buffered MFMA GEMM (A=qb bf16, B=wbT), M=64 N=256 ----------
// Pipeline: batches of 5 global_load_lds (1 A + 4 B) per wave per iter; gates use raw
// s_waitcnt vmcnt(5) + s_barrier so the next batch stays in flight across the barrier.
__global__ __launch_bounds__(256) void k_ga(const unsigned short* __restrict__ qb,
                                            const unsigned short* __restrict__ wbT,
                                            const float* __restrict__ bo1, const float* __restrict__ Wo2,
                                            const float* __restrict__ bo2,
                                            const float* __restrict__ bc1, const float* __restrict__ Wc2,
                                            const float* __restrict__ bc2,
                                            const float* __restrict__ ic,
                                            float* __restrict__ out_kp, float* __restrict__ out_conf) {
    __shared__ __align__(16) char smem[40960];   // A dbuf [0,8192), B dbuf [8192,40960)
    int mb = blockIdx.x >> 1;
    int nb = blockIdx.x & 1;
    int t = threadIdx.x;
    int wv = t >> 6;
    int lane = t & 63;
    int r = lane & 15;
    int qg = lane >> 4;
    int as = (qg ^ swz(r)) << 4;   // swizzled chunk byte offset for frag reads

    f32x4 acc[4][4];
    #pragma unroll
    for (int i = 0; i < 4; i++)
        #pragma unroll
        for (int j = 0; j < 4; j++) { f32x4 z = {0.f, 0.f, 0.f, 0.f}; acc[i][j] = z; }

    const char* aG = (const char*)qb + (size_t)mb * 65536 + wv * 1024 + lane * 16;
    const char* bG = (const char*)wbT + nb * 16384 + wv * 4096 + lane * 16;

    // prologue: batches 0 and 1
    #pragma unroll
    for (int b = 0; b < 2; b++) {
        ldg_lds16(aG + b * 4096, smem + b * 4096 + wv * 1024);
        #pragma unroll
        for (int i = 0; i < 4; i++)
            ldg_lds16(bG + b * 32768 + i * 1024, smem + 8192 + b * 16384 + wv * 4096 + i * 1024);
    }
    __builtin_amdgcn_sched_barrier(0);

    for (int p = 0; p < 16; p++) {
        if (p < 15) __builtin_amdgcn_s_waitcnt(0x0F75);  // vmcnt(5): batch p done, p+1 in flight
        else        __builtin_amdgcn_s_waitcnt(0x0F70);  // vmcnt(0): last batch
        __builtin_amdgcn_s_barrier();
        __builtin_amdgcn_sched_barrier(0);
        int bi = p & 1;
        const char* ab = smem + bi * 4096;
        const char* bb = smem + 8192 + bi * 16384;
        bf16x8 af[4], bf[4];
        #pragma unroll
        for (int mt = 0; mt < 4; mt++)
            af[mt] = *(const bf16x8*)(ab + (mt * 16 + r) * 64 + as);
        #pragma unroll
        for (int nt = 0; nt < 4; nt++)
            bf[nt] = *(const bf16x8*)(bb + (wv * 64 + nt * 16 + r) * 64 + as);
        #pragma unroll
        for (int mt = 0; mt < 4; mt++)
            #pragma unroll
            for (int nt = 0; nt < 4; nt++)
                acc[mt][nt] = __builtin_amdgcn_mfma_f32_16x16x32_bf16(af[mt], bf[nt], acc[mt][nt], 0, 0, 0);
        __builtin_amdgcn_sched_barrier(0);
        __builtin_amdgcn_s_barrier();   // all waves done reading buf bi
        if (p < 14) {
            int b2 = p + 2;
            ldg_lds16(aG + b2 * 4096, smem + bi * 4096 + wv * 1024);
            #pragma unroll
            for (int i = 0; i < 4; i++)
                ldg_lds16(bG + (size_t)b2 * 32768 + i * 1024, smem + 8192 + bi * 16384 + wv * 4096 + i * 1024);
        }
        __builtin_amdgcn_sched_barrier(0);
    }
    __syncthreads();
    epilogue(acc, smem, mb, nb, t, wv, lane, r, bo1, Wo2, bo2, bc1, Wc2, bc2, ic, out_kp, out_conf);
}

// ---------------- k_gs: fallback synchronous GEMM (A from f32 qf, B from wbT), same layouts ------
__global__ __launch_bounds__(256) void k_gs(const float* __restrict__ qf,
                                            const unsigned short* __restrict__ wbT,
                                            const float* __restrict__ bo1, const float* __restrict__ Wo2,
                                            const float* __restrict__ bo2,
                                            const float* __restrict__ bc1, const float* __restrict__ Wc2,
                                            const float* __restrict__ bc2,
                                            const float* __restrict__ ic,
                                            float* __restrict__ out_kp, float* __restrict__ out_conf) {
    __shared__ __align__(16) char smem[40960];   // A [0,4096), B [8192,24576)
    int mb = blockIdx.x >> 1;
    int nb = blockIdx.x & 1;
    int t = threadIdx.x;
    int wv = t >> 6;
    int lane = t & 63;
    int r = lane & 15;
    int qg = lane >> 4;
    int as = (qg ^ swz(r)) << 4;

    f32x4 acc[4][4];
    #pragma unroll
    for (int i = 0; i < 4; i++)
        #pragma unroll
        for (int j = 0; j < 4; j++) { f32x4 z = {0.f, 0.f, 0.f, 0.f}; acc[i][j] = z; }

    int am = t >> 2;
    int akc = t & 3;
    const float* aptr = qf + ((size_t)(mb * 64 + am)) * DIM + akc * 8;
    const char* bGb = (const char*)wbT + nb * 16384 + t * 16;
    int awoff = am * 64 + ((akc ^ swz(am)) << 4);

    float4 A0 = *(const float4*)(aptr);
    float4 A1 = *(const float4*)(aptr + 4);
    uint4 Bp[4];
    #pragma unroll
    for (int j = 0; j < 4; j++) Bp[j] = *(const uint4*)(bGb + j * 4096);

    for (int it = 0; it < 16; it++) {
        unsigned int p0 = f2bf(A0.x) | ((unsigned int)f2bf(A0.y) << 16);
        unsigned int p1 = f2bf(A0.z) | ((unsigned int)f2bf(A0.w) << 16);
        unsigned int p2 = f2bf(A1.x) | ((unsigned int)f2bf(A1.y) << 16);
        unsigned int p3 = f2bf(A1.z) | ((unsigned int)f2bf(A1.w) << 16);
        __syncthreads();
        *(uint4*)(smem + awoff) = make_uint4(p0, p1, p2, p3);
        #pragma unroll
        for (int j = 0; j < 4; j++) *(uint4*)(smem + 8192 + j * 4096 + t * 16) = Bp[j];
        __syncthreads();
        if (it < 15) {
            int k1 = (it + 1) * 32;
            A0 = *(const float4*)(aptr + k1);
            A1 = *(const float4*)(aptr + k1 + 4);
            #pragma unroll
            for (int j = 0; j < 4; j++) Bp[j] = *(const uint4*)(bGb + (size_t)(it + 1) * 32768 + j * 4096);
        }
        bf16x8 af[4], bf[4];
        #pragma unroll
        for (int mt = 0; mt < 4; mt++)
            af[mt] = *(const bf16x8*)(smem + (mt * 16 + r) * 64 + as);
        #pragma unroll
        for (int nt = 0; nt < 4; nt++)
            bf[nt] = *(const bf16x8*)(smem + 8192 + (wv * 64 + nt * 16 + r) * 64 + as);
        #pragma unroll
        for (int mt = 0; mt < 4; mt++)
            #pragma unroll
            for (int nt = 0; nt < 4; nt++)
                acc[mt][nt] = __builtin_amdgcn_mfma_f32_16x16x32_bf16(af[mt], bf[nt], acc[mt][nt], 0, 0, 0);
    }
    __syncthreads();
    epilogue(acc, smem, mb, nb, t, wv, lane, r, bo1, Wo2, bo2, bc1, Wc2, bc2, ic, out_kp, out_conf);
}

extern "C" void kernel_launch(void* const* d_in, const int* in_sizes, int n_in,
                              void* d_out, int out_size, void* d_ws, size_t ws_size,
                              hipStream_t stream) {
    const float* sf = (const float*)d_in[0];
    const float* qf = (const float*)d_in[2];
    const float* ic = (const float*)d_in[3];
    const float* W1 = (const float*)d_in[4];
    const float* b1 = (const float*)d_in[5];
    const float* W2 = (const float*)d_in[6];
    const float* b2 = (const float*)d_in[7];
    const float* Wo1 = (const float*)d_in[8];
    const float* bo1 = (const float*)d_in[9];
    const float* Wo2 = (const float*)d_in[10];
    const float* bo2 = (const float*)d_in[11];
    const float* Wc1 = (const float*)d_in[12];
    const float* bc1 = (const float*)d_in[13];
    const float* Wc2 = (const float*)d_in[14];
    const float* bc2 = (const float*)d_in[15];
    const float* temp = (const float*)d_in[16];

    float* out = (float*)d_out;
    float* out_kp = out;                   // 65536*17*2
    float* out_conf = out + 2228224;       // 65536*17
    float* out_dist = out + 3342336;       // 65536*5*17
    float* out_class = out + 8912896;      // 65536
    float* out_proto = out + 8978432;      // 5*17*512

    char* ws = (char*)d_ws;
    float* ws_h1 = (float*)ws;                              // 25*512 f32
    float* ws_proto = (float*)(ws + 51200);                 // 5*512 f32
    float* ws_pn = (float*)(ws + 61440);                    // 5 f32
    unsigned short* ws_wbT = (unsigned short*)(ws + 65536); // 512KB tiled/swizzled [Wo1|Wc1]
    unsigned short* ws_qb = (unsigned short*)(ws + 1048576); // 67MB tiled/swizzled bf16 qf
    int use_qb = (ws_size >= (size_t)1048576 + 67108864) ? 1 : 0;

    hipLaunchKernelGGL(k_l1, dim3(114), dim3(256), 0, stream, sf, W1, b1, Wo1, Wc1, ws_h1, ws_wbT);
    hipLaunchKernelGGL(k_l2, dim3(5), dim3(256), 0, stream, ws_h1, W2, b2, ws_proto, ws_pn);
    hipLaunchKernelGGL(k_cd, dim3(2048), dim3(256), 0, stream, qf, ws_proto, ws_pn, temp,
                       out_dist, out_class, out_proto, ws_qb, use_qb);
    if (use_qb) {
        hipLaunchKernelGGL(k_ga, dim3(2048), dim3(256), 0, stream, ws_qb, ws_wbT,
                           bo1, Wo2, bo2, bc1, Wc2, bc2, ic, out_kp, out_conf);
    } else {
        hipLaunchKernelGGL(k_gs, dim3(2048), dim3(256), 0, stream, qf, ws_wbT,
                           bo1, Wo2, bo2, bc1, Wc2, bc2, ic, out_kp, out_conf);
    }
}